// Round 2
// baseline (245.454 us; speedup 1.0000x reference)
//
#include <hip/hip_runtime.h>

#define N_TOK 2048
#define DD 512
#define FF 512
#define EE 64
#define TK 6
#define NG 66
#define RSLOT 12288   // N_TOK*TK
#define NSLOT 16384   // RSLOT + 2*N_TOK
#define BM1 128
#define BN1 64

typedef float f32x4 __attribute__((ext_vector_type(4)));
typedef __bf16 bf16x8 __attribute__((ext_vector_type(8)));
typedef short s16x8 __attribute__((ext_vector_type(8)));

__device__ __forceinline__ short f2bf(float f) {
  unsigned u = __builtin_bit_cast(unsigned, f);
  u = (u + 0x7fffu + ((u >> 16) & 1u)) >> 16;
  return (short)u;
}

// ---------------- router: logits -> exp(l-max) -> top-6 + counts ----------------
__global__ void router_k(const float* __restrict__ x, const float* __restrict__ Wr,
                         int* __restrict__ top_i, float* __restrict__ top_w,
                         int* __restrict__ cnt) {
  int wave = threadIdx.x >> 6, lane = threadIdx.x & 63;
  int t0 = (blockIdx.x * 4 + wave) * 4;   // 4 tokens per wave
  const float* x0 = x + (size_t)t0 * DD;
  float a0 = 0.f, a1 = 0.f, a2 = 0.f, a3 = 0.f;
  for (int k = 0; k < DD; ++k) {
    float wv = Wr[k * EE + lane];
    a0 = fmaf(x0[k], wv, a0);
    a1 = fmaf(x0[DD + k], wv, a1);
    a2 = fmaf(x0[2 * DD + k], wv, a2);
    a3 = fmaf(x0[3 * DD + k], wv, a3);
  }
  float accs[4] = {a0, a1, a2, a3};
#pragma unroll
  for (int tt = 0; tt < 4; ++tt) {
    int t = t0 + tt;
    float acc = accs[tt];
    float m = acc;
#pragma unroll
    for (int s = 32; s; s >>= 1) m = fmaxf(m, __shfl_xor(m, s));
    float p = __expf(acc - m);   // unnormalized softmax; ratios identical
    int wi[TK]; float wv[TK];
#pragma unroll
    for (int it = 0; it < TK; ++it) {
      float v = p;
#pragma unroll
      for (int s = 32; s; s >>= 1) v = fmaxf(v, __shfl_xor(v, s));
      unsigned long long b = __ballot(p == v);
      int idx = __ffsll((unsigned long long)b) - 1;
      wi[it] = idx; wv[it] = v;
      if (lane == idx) p = -1.f;
    }
    float wsum = 0.f;
#pragma unroll
    for (int it = 0; it < TK; ++it) wsum += wv[it];
    if (lane < TK) {
      int si = 0; float sv = 0.f;
#pragma unroll
      for (int it = 0; it < TK; ++it) if (lane == it) { si = wi[it]; sv = wv[it]; }
      top_i[t * TK + lane] = si;
      top_w[t * TK + lane] = sv / wsum;
      atomicAdd(&cnt[si], 1);
    }
  }
}

// ---------------- offsets: prefix sum over experts, zero fill ----------------
__global__ void offsets_k(const int* __restrict__ cnt, int* __restrict__ goff,
                          int* __restrict__ fill) {
  int i = threadIdx.x;
  if (i < EE) fill[i] = 0;
  if (i == 0) {
    int s = 0;
    for (int e = 0; e < EE; ++e) { goff[e] = s; s += cnt[e]; }
    goff[EE] = RSLOT;
    goff[EE + 1] = RSLOT + N_TOK;
    goff[EE + 2] = RSLOT + 2 * N_TOK;
  }
}

// ---------------- scatter: fill expert buckets (+ shared identity buckets) -----
__global__ void scatter_k(const int* __restrict__ top_i, const float* __restrict__ top_w,
                          const int* __restrict__ goff, int* __restrict__ fill,
                          int* __restrict__ btok, float* __restrict__ bw) {
  int idx = blockIdx.x * blockDim.x + threadIdx.x;
  if (idx < RSLOT) {
    int e = top_i[idx];
    int pos = goff[e] + atomicAdd(&fill[e], 1);
    btok[pos] = idx / TK;
    bw[pos] = top_w[idx];
  } else if (idx < NSLOT) {
    int j = idx - RSLOT;
    btok[idx] = j & (N_TOK - 1);
    bw[idx] = 1.0f;
  }
}

// ---------------- out = x (residual init) ----------------
__global__ void initout_k(const float* __restrict__ x, float* __restrict__ out, int n4) {
  int i = blockIdx.x * blockDim.x + threadIdx.x;
  if (i < n4) reinterpret_cast<f32x4*>(out)[i] = reinterpret_cast<const f32x4*>(x)[i];
}

// ---------------- GEMM1: H = silu(X*Wg) * (X*Wu), gathered rows -------------
// 128x64 block, 4 waves stacked on M (32 rows x 64 cols each), reg-prefetch pipeline
__global__ __launch_bounds__(256) void gemm1_k(
    const float* __restrict__ x, const float* __restrict__ Wg, const float* __restrict__ Wu,
    const float* __restrict__ sWg, const float* __restrict__ sWu,
    const int* __restrict__ goff, const int* __restrict__ btok,
    short* __restrict__ H) {
  int g = blockIdx.z;
  int s0g = goff[g], cnt = goff[g + 1] - s0g;
  int mt = blockIdx.y;
  if (mt * BM1 >= cnt) return;
  int n0 = blockIdx.x * BN1;
  const float* wgp = (g < EE) ? Wg + (size_t)g * DD * FF : sWg + (size_t)(g - EE) * DD * FF;
  const float* wup = (g < EE) ? Wu + (size_t)g * DD * FF : sWu + (size_t)(g - EE) * DD * FF;

  __shared__ short laA[2][4][BM1][8];
  __shared__ short lbG[2][4][BN1][8];
  __shared__ short lbU[2][4][BN1][8];

  int tid = threadIdx.x;
  int lane = tid & 63;
  int w = tid >> 6;
  int lr = lane & 15, lgq = lane >> 4;

  int arow = tid >> 1, ahalf = tid & 1;   // A staging: row, k-half(16)
  int bcol = tid & 63, bkp = tid >> 6;    // B staging: col, kblk(8)

  int s0 = s0g + mt * BM1;
  int aslot = (mt * BM1 + arow < cnt) ? s0 + arow : s0;
  const float* xrow = x + (size_t)btok[aslot] * DD + ahalf * 16;
  const float* gbase = wgp + n0 + bcol;
  const float* ubase = wup + n0 + bcol;

  f32x4 accg[2][4], accu[2][4];
#pragma unroll
  for (int i = 0; i < 2; ++i)
#pragma unroll
    for (int j = 0; j < 4; ++j) {
      accg[i][j] = f32x4{0.f, 0.f, 0.f, 0.f};
      accu[i][j] = f32x4{0.f, 0.f, 0.f, 0.f};
    }

  f32x4 ar0, ar1, ar2, ar3;
  float og[8], ou[8];

  auto LOAD = [&](int kt) {
    const float* p = xrow + kt * 32;
    ar0 = *reinterpret_cast<const f32x4*>(p);
    ar1 = *reinterpret_cast<const f32x4*>(p + 4);
    ar2 = *reinterpret_cast<const f32x4*>(p + 8);
    ar3 = *reinterpret_cast<const f32x4*>(p + 12);
    int kb = kt * 32 + bkp * 8;
#pragma unroll
    for (int i = 0; i < 8; ++i) {
      og[i] = gbase[(size_t)(kb + i) * FF];
      ou[i] = ubase[(size_t)(kb + i) * FF];
    }
  };
  auto STORE = [&](int b) {
    s16x8 o0, o1;
    o0[0] = f2bf(ar0[0]); o0[1] = f2bf(ar0[1]); o0[2] = f2bf(ar0[2]); o0[3] = f2bf(ar0[3]);
    o0[4] = f2bf(ar1[0]); o0[5] = f2bf(ar1[1]); o0[6] = f2bf(ar1[2]); o0[7] = f2bf(ar1[3]);
    o1[0] = f2bf(ar2[0]); o1[1] = f2bf(ar2[1]); o1[2] = f2bf(ar2[2]); o1[3] = f2bf(ar2[3]);
    o1[4] = f2bf(ar3[0]); o1[5] = f2bf(ar3[1]); o1[6] = f2bf(ar3[2]); o1[7] = f2bf(ar3[3]);
    *reinterpret_cast<s16x8*>(&laA[b][2 * ahalf][arow][0]) = o0;
    *reinterpret_cast<s16x8*>(&laA[b][2 * ahalf + 1][arow][0]) = o1;
    s16x8 cg, cu;
#pragma unroll
    for (int i = 0; i < 8; ++i) { cg[i] = f2bf(og[i]); cu[i] = f2bf(ou[i]); }
    *reinterpret_cast<s16x8*>(&lbG[b][bkp][bcol][0]) = cg;
    *reinterpret_cast<s16x8*>(&lbU[b][bkp][bcol][0]) = cu;
  };
  auto COMPUTE = [&](int b) {
    bf16x8 af[2], bg[4], bu[4];
#pragma unroll
    for (int i = 0; i < 2; ++i)
      af[i] = *reinterpret_cast<const bf16x8*>(&laA[b][lgq][w * 32 + i * 16 + lr][0]);
#pragma unroll
    for (int j = 0; j < 4; ++j) {
      bg[j] = *reinterpret_cast<const bf16x8*>(&lbG[b][lgq][j * 16 + lr][0]);
      bu[j] = *reinterpret_cast<const bf16x8*>(&lbU[b][lgq][j * 16 + lr][0]);
    }
#pragma unroll
    for (int i = 0; i < 2; ++i)
#pragma unroll
      for (int j = 0; j < 4; ++j) {
        accg[i][j] = __builtin_amdgcn_mfma_f32_16x16x32_bf16(af[i], bg[j], accg[i][j], 0, 0, 0);
        accu[i][j] = __builtin_amdgcn_mfma_f32_16x16x32_bf16(af[i], bu[j], accu[i][j], 0, 0, 0);
      }
  };

  LOAD(0);
  STORE(0);
  __syncthreads();
#pragma unroll 1
  for (int kt = 0; kt < DD / 32; ++kt) {
    int cur = kt & 1;
    if (kt < DD / 32 - 1) LOAD(kt + 1);
    COMPUTE(cur);
    if (kt < DD / 32 - 1) {
      STORE(cur ^ 1);
      __syncthreads();
    }
  }

  // epilogue: h = silu(g)*u -> bf16 H
#pragma unroll
  for (int i = 0; i < 2; ++i)
#pragma unroll
    for (int j = 0; j < 4; ++j)
#pragma unroll
      for (int r = 0; r < 4; ++r) {
        int mrow = w * 32 + i * 16 + lgq * 4 + r;
        if (mt * BM1 + mrow < cnt) {
          float gg = accg[i][j][r];
          float uu = accu[i][j][r];
          float hv = (gg / (1.f + __expf(-gg))) * uu;
          int col = n0 + j * 16 + lr;
          H[(size_t)(s0 + mrow) * FF + col] = f2bf(hv);
        }
      }
}

// ---------------- GEMM2: out[tok] += w * (H * Wd) ----------------
__global__ __launch_bounds__(256) void gemm2_k(
    const short* __restrict__ H, const float* __restrict__ Wd, const float* __restrict__ sWd,
    const int* __restrict__ goff, const int* __restrict__ btok, const float* __restrict__ bw,
    float* __restrict__ out) {
  int g = blockIdx.z;
  int s0g = goff[g], cnt = goff[g + 1] - s0g;
  int mt = blockIdx.y;
  if (mt * BM1 >= cnt) return;
  int n0 = blockIdx.x * BN1;
  const float* wdp = (g < EE) ? Wd + (size_t)g * FF * DD : sWd + (size_t)(g - EE) * FF * DD;

  __shared__ short laA[2][4][BM1][8];
  __shared__ short lbB[2][4][BN1][8];

  int tid = threadIdx.x;
  int lane = tid & 63;
  int w = tid >> 6;
  int lr = lane & 15, lgq = lane >> 4;

  int arow = tid >> 1, ahalf = tid & 1;
  int bcol = tid & 63, bkp = tid >> 6;

  int s0 = s0g + mt * BM1;
  int aslot = (mt * BM1 + arow < cnt) ? s0 + arow : s0;
  const short* hrow = H + (size_t)aslot * FF + ahalf * 16;
  const float* dbase = wdp + n0 + bcol;

  f32x4 acc[2][4];
#pragma unroll
  for (int i = 0; i < 2; ++i)
#pragma unroll
    for (int j = 0; j < 4; ++j) acc[i][j] = f32x4{0.f, 0.f, 0.f, 0.f};

  s16x8 h0, h1;
  float od[8];

  auto LOAD = [&](int kt) {
    const short* p = hrow + kt * 32;
    h0 = *reinterpret_cast<const s16x8*>(p);
    h1 = *reinterpret_cast<const s16x8*>(p + 8);
    int kb = kt * 32 + bkp * 8;
#pragma unroll
    for (int i = 0; i < 8; ++i) od[i] = dbase[(size_t)(kb + i) * DD];
  };
  auto STORE = [&](int b) {
    *reinterpret_cast<s16x8*>(&laA[b][2 * ahalf][arow][0]) = h0;
    *reinterpret_cast<s16x8*>(&laA[b][2 * ahalf + 1][arow][0]) = h1;
    s16x8 cd;
#pragma unroll
    for (int i = 0; i < 8; ++i) cd[i] = f2bf(od[i]);
    *reinterpret_cast<s16x8*>(&lbB[b][bkp][bcol][0]) = cd;
  };
  auto COMPUTE = [&](int b) {
    bf16x8 af[2], bd[4];
#pragma unroll
    for (int i = 0; i < 2; ++i)
      af[i] = *reinterpret_cast<const bf16x8*>(&laA[b][lgq][w * 32 + i * 16 + lr][0]);
#pragma unroll
    for (int j = 0; j < 4; ++j)
      bd[j] = *reinterpret_cast<const bf16x8*>(&lbB[b][lgq][j * 16 + lr][0]);
#pragma unroll
    for (int i = 0; i < 2; ++i)
#pragma unroll
      for (int j = 0; j < 4; ++j)
        acc[i][j] = __builtin_amdgcn_mfma_f32_16x16x32_bf16(af[i], bd[j], acc[i][j], 0, 0, 0);
  };

  LOAD(0);
  STORE(0);
  __syncthreads();
#pragma unroll 1
  for (int kt = 0; kt < FF / 32; ++kt) {
    int cur = kt & 1;
    if (kt < FF / 32 - 1) LOAD(kt + 1);
    COMPUTE(cur);
    if (kt < FF / 32 - 1) {
      STORE(cur ^ 1);
      __syncthreads();
    }
  }

#pragma unroll
  for (int i = 0; i < 2; ++i)
#pragma unroll
    for (int r = 0; r < 4; ++r) {
      int mrow = w * 32 + i * 16 + lgq * 4 + r;
      if (mt * BM1 + mrow < cnt) {
        int slot = s0 + mrow;
        int tok = btok[slot];
        float wv = bw[slot];
#pragma unroll
        for (int j = 0; j < 4; ++j) {
          int col = n0 + j * 16 + lr;
          atomicAdd(&out[(size_t)tok * DD + col], acc[i][j][r] * wv);
        }
      }
    }
}

extern "C" void kernel_launch(void* const* d_in, const int* in_sizes, int n_in,
                              void* d_out, int out_size, void* d_ws, size_t ws_size,
                              hipStream_t stream) {
  const float* x   = (const float*)d_in[0];
  const float* Wr  = (const float*)d_in[1];
  const float* sWg = (const float*)d_in[2];
  const float* sWu = (const float*)d_in[3];
  const float* sWd = (const float*)d_in[4];
  const float* Wg  = (const float*)d_in[5];
  const float* Wu  = (const float*)d_in[6];
  const float* Wd  = (const float*)d_in[7];
  float* out = (float*)d_out;

  char* wsb = (char*)d_ws;
  size_t off = 0;
  short* H = (short*)(wsb + off);    off += (size_t)NSLOT * FF * 2;     // 16 MB
  int*   top_i = (int*)(wsb + off);  off += (size_t)RSLOT * 4;
  float* top_w = (float*)(wsb + off); off += (size_t)RSLOT * 4;
  int*   btok = (int*)(wsb + off);   off += (size_t)NSLOT * 4;
  float* bwt  = (float*)(wsb + off); off += (size_t)NSLOT * 4;
  int*   cnt  = (int*)(wsb + off);   off += 256;
  int*   fill = (int*)(wsb + off);   off += 256;
  int*   goff = (int*)(wsb + off);   off += 256;

  hipMemsetAsync(cnt, 0, 256, stream);
  router_k<<<N_TOK / 16, 256, 0, stream>>>(x, Wr, top_i, top_w, cnt);
  offsets_k<<<1, 64, 0, stream>>>(cnt, goff, fill);
  scatter_k<<<NSLOT / 256, 256, 0, stream>>>(top_i, top_w, goff, fill, btok, bwt);
  int n4 = out_size / 4;
  initout_k<<<(n4 + 255) / 256, 256, 0, stream>>>(x, out, n4);
  dim3 grid1(FF / BN1, (N_TOK + BM1 - 1) / BM1, NG);
  gemm1_k<<<grid1, 256, 0, stream>>>(x, Wg, Wu, sWg, sWu, goff, btok, H);
  dim3 grid2(DD / BN1, (N_TOK + BM1 - 1) / BM1, NG);
  gemm2_k<<<grid2, 256, 0, stream>>>(H, Wd, sWd, goff, btok, bwt, out);
}

// Round 3
// 199.700 us; speedup vs baseline: 1.2291x; 1.2291x over previous
//
#include <hip/hip_runtime.h>

#define N_TOK 2048
#define DD 512
#define FF 512
#define EE 64
#define TK 6
#define NG 66
#define RSLOT 12288   // N_TOK*TK
#define NSLOT 16384   // RSLOT + 2*N_TOK
#define BM 64
#define BN 64
#define NT1 (DD / 32)
#define NT2 (FF / 32)

typedef float f32x4 __attribute__((ext_vector_type(4)));
typedef __bf16 bf16x8 __attribute__((ext_vector_type(8)));
typedef short s16x8 __attribute__((ext_vector_type(8)));

__device__ __forceinline__ unsigned cvtpk(float lo, float hi) {
  unsigned r;
  asm("v_cvt_pk_bf16_f32 %0, %1, %2" : "=v"(r) : "v"(lo), "v"(hi));
  return r;
}

// ---------------- router: logits -> exp(l-max) -> top-6 + counts ----------------
__global__ void router_k(const float* __restrict__ x, const float* __restrict__ Wr,
                         int* __restrict__ top_i, float* __restrict__ top_w,
                         int* __restrict__ cnt) {
  int wave = threadIdx.x >> 6, lane = threadIdx.x & 63;
  int t0 = (blockIdx.x * 4 + wave) * 4;   // 4 tokens per wave
  const float* x0 = x + (size_t)t0 * DD;
  float a0 = 0.f, a1 = 0.f, a2 = 0.f, a3 = 0.f;
  for (int k = 0; k < DD; ++k) {
    float wv = Wr[k * EE + lane];
    a0 = fmaf(x0[k], wv, a0);
    a1 = fmaf(x0[DD + k], wv, a1);
    a2 = fmaf(x0[2 * DD + k], wv, a2);
    a3 = fmaf(x0[3 * DD + k], wv, a3);
  }
  float accs[4] = {a0, a1, a2, a3};
#pragma unroll
  for (int tt = 0; tt < 4; ++tt) {
    int t = t0 + tt;
    float acc = accs[tt];
    float m = acc;
#pragma unroll
    for (int s = 32; s; s >>= 1) m = fmaxf(m, __shfl_xor(m, s));
    float p = __expf(acc - m);   // unnormalized softmax; ratios identical
    int wi[TK]; float wv[TK];
#pragma unroll
    for (int it = 0; it < TK; ++it) {
      float v = p;
#pragma unroll
      for (int s = 32; s; s >>= 1) v = fmaxf(v, __shfl_xor(v, s));
      unsigned long long b = __ballot(p == v);
      int idx = __ffsll((unsigned long long)b) - 1;
      wi[it] = idx; wv[it] = v;
      if (lane == idx) p = -1.f;
    }
    float wsum = 0.f;
#pragma unroll
    for (int it = 0; it < TK; ++it) wsum += wv[it];
    if (lane < TK) {
      int si = 0; float sv = 0.f;
#pragma unroll
      for (int it = 0; it < TK; ++it) if (lane == it) { si = wi[it]; sv = wv[it]; }
      top_i[t * TK + lane] = si;
      top_w[t * TK + lane] = sv / wsum;
      atomicAdd(&cnt[si], 1);
    }
  }
}

// ---------------- offsets: prefix sum over experts, zero fill ----------------
__global__ void offsets_k(const int* __restrict__ cnt, int* __restrict__ goff,
                          int* __restrict__ fill) {
  int i = threadIdx.x;
  if (i < EE) fill[i] = 0;
  if (i == 0) {
    int s = 0;
    for (int e = 0; e < EE; ++e) { goff[e] = s; s += cnt[e]; }
    goff[EE] = RSLOT;
    goff[EE + 1] = RSLOT + N_TOK;
    goff[EE + 2] = RSLOT + 2 * N_TOK;
  }
}

// ---------------- scatter: fill expert buckets (+ shared identity buckets) -----
__global__ void scatter_k(const int* __restrict__ top_i, const float* __restrict__ top_w,
                          const int* __restrict__ goff, int* __restrict__ fill,
                          int* __restrict__ btok, float* __restrict__ bw) {
  int idx = blockIdx.x * blockDim.x + threadIdx.x;
  if (idx < RSLOT) {
    int e = top_i[idx];
    int pos = goff[e] + atomicAdd(&fill[e], 1);
    btok[pos] = idx / TK;
    bw[pos] = top_w[idx];
  } else if (idx < NSLOT) {
    int j = idx - RSLOT;
    btok[idx] = j & (N_TOK - 1);
    bw[idx] = 1.0f;
  }
}

// ---------------- out = x (residual init) ----------------
__global__ void initout_k(const float* __restrict__ x, float* __restrict__ out, int n4) {
  int i = blockIdx.x * blockDim.x + threadIdx.x;
  if (i < n4) reinterpret_cast<f32x4*>(out)[i] = reinterpret_cast<const f32x4*>(x)[i];
}

// ---------------- GEMM1: H = silu(X*Wg) * (X*Wu), gathered rows -------------
// 64x64 block, 4 waves in 2x2, 2-deep register-prefetch pipeline
__global__ __launch_bounds__(256) void gemm1_k(
    const float* __restrict__ x, const float* __restrict__ Wg, const float* __restrict__ Wu,
    const float* __restrict__ sWg, const float* __restrict__ sWu,
    const int* __restrict__ goff, const int* __restrict__ btok,
    short* __restrict__ H) {
  int g = blockIdx.z;
  int s0g = goff[g], cnt = goff[g + 1] - s0g;
  int mt = blockIdx.y;
  if (mt * BM >= cnt) return;
  int n0 = blockIdx.x * BN;
  const float* wgp = (g < EE) ? Wg + (size_t)g * DD * FF : sWg + (size_t)(g - EE) * DD * FF;
  const float* wup = (g < EE) ? Wu + (size_t)g * DD * FF : sWu + (size_t)(g - EE) * DD * FF;

  __shared__ short laA[2][4][BM][8];
  __shared__ short lbG[2][4][BN][8];
  __shared__ short lbU[2][4][BN][8];

  int tid = threadIdx.x;
  int lane = tid & 63;
  int w = tid >> 6;
  int wr = w >> 1, wc = w & 1;
  int lr = lane & 15, lgq = lane >> 4;

  int arow = tid >> 2, aseg = tid & 3;    // A staging: 4 threads/row, 8 k each
  int bcol = tid & 63, bkp = tid >> 6;    // B staging: col, kblk of 8

  int s0 = s0g + mt * BM;
  int aslot = (mt * BM + arow < cnt) ? s0 + arow : s0;
  const float* xrow = x + (size_t)btok[aslot] * DD + aseg * 8;
  const float* gb = wgp + n0 + bcol;
  const float* ub = wup + n0 + bcol;

  f32x4 accg[2][2], accu[2][2];
#pragma unroll
  for (int i = 0; i < 2; ++i)
#pragma unroll
    for (int j = 0; j < 2; ++j) {
      accg[i][j] = f32x4{0.f, 0.f, 0.f, 0.f};
      accu[i][j] = f32x4{0.f, 0.f, 0.f, 0.f};
    }

  // two register prefetch sets
  f32x4 a0_0, a0_1, a1_0, a1_1;
  float g0[8], u0[8], g1[8], u1[8];

#define LOAD1(S, kt) do { \
    const float* _p = xrow + (kt) * 32; \
    a##S##_0 = *reinterpret_cast<const f32x4*>(_p); \
    a##S##_1 = *reinterpret_cast<const f32x4*>(_p + 4); \
    int _kb = (kt) * 32 + bkp * 8; \
    _Pragma("unroll") \
    for (int _i = 0; _i < 8; ++_i) { \
      g##S[_i] = gb[(size_t)((_kb + _i) * FF)]; \
      u##S[_i] = ub[(size_t)((_kb + _i) * FF)]; \
    } \
  } while (0)

#define STORE1(S, b) do { \
    uint4 _va; \
    _va.x = cvtpk(a##S##_0[0], a##S##_0[1]); _va.y = cvtpk(a##S##_0[2], a##S##_0[3]); \
    _va.z = cvtpk(a##S##_1[0], a##S##_1[1]); _va.w = cvtpk(a##S##_1[2], a##S##_1[3]); \
    *reinterpret_cast<uint4*>(&laA[b][aseg][arow][0]) = _va; \
    uint4 _vg, _vu; \
    _vg.x = cvtpk(g##S[0], g##S[1]); _vg.y = cvtpk(g##S[2], g##S[3]); \
    _vg.z = cvtpk(g##S[4], g##S[5]); _vg.w = cvtpk(g##S[6], g##S[7]); \
    _vu.x = cvtpk(u##S[0], u##S[1]); _vu.y = cvtpk(u##S[2], u##S[3]); \
    _vu.z = cvtpk(u##S[4], u##S[5]); _vu.w = cvtpk(u##S[6], u##S[7]); \
    *reinterpret_cast<uint4*>(&lbG[b][bkp][bcol][0]) = _vg; \
    *reinterpret_cast<uint4*>(&lbU[b][bkp][bcol][0]) = _vu; \
  } while (0)

#define COMPUTE1(b) do { \
    bf16x8 _af[2], _bg[2], _bu[2]; \
    _Pragma("unroll") \
    for (int _i = 0; _i < 2; ++_i) \
      _af[_i] = *reinterpret_cast<const bf16x8*>(&laA[b][lgq][wr * 32 + _i * 16 + lr][0]); \
    _Pragma("unroll") \
    for (int _j = 0; _j < 2; ++_j) { \
      _bg[_j] = *reinterpret_cast<const bf16x8*>(&lbG[b][lgq][wc * 32 + _j * 16 + lr][0]); \
      _bu[_j] = *reinterpret_cast<const bf16x8*>(&lbU[b][lgq][wc * 32 + _j * 16 + lr][0]); \
    } \
    _Pragma("unroll") \
    for (int _i = 0; _i < 2; ++_i) \
      _Pragma("unroll") \
      for (int _j = 0; _j < 2; ++_j) { \
        accg[_i][_j] = __builtin_amdgcn_mfma_f32_16x16x32_bf16(_af[_i], _bg[_j], accg[_i][_j], 0, 0, 0); \
        accu[_i][_j] = __builtin_amdgcn_mfma_f32_16x16x32_bf16(_af[_i], _bu[_j], accu[_i][_j], 0, 0, 0); \
      } \
  } while (0)

  LOAD1(0, 0);
  LOAD1(1, 1);
  STORE1(0, 0);
  __syncthreads();
#pragma unroll 1
  for (int kt = 0; kt < NT1; kt += 2) {
    if (kt + 2 < NT1) LOAD1(0, kt + 2);
    COMPUTE1(0);
    STORE1(1, 1);
    __syncthreads();
    if (kt + 3 < NT1) LOAD1(1, kt + 3);
    COMPUTE1(1);
    if (kt + 2 < NT1) {
      STORE1(0, 0);
    }
    __syncthreads();
  }

  // epilogue: h = silu(g)*u -> bf16 H
#pragma unroll
  for (int i = 0; i < 2; ++i)
#pragma unroll
    for (int j = 0; j < 2; ++j)
#pragma unroll
      for (int r = 0; r < 4; ++r) {
        int mrow = wr * 32 + i * 16 + lgq * 4 + r;
        if (mt * BM + mrow < cnt) {
          float gg = accg[i][j][r];
          float uu = accu[i][j][r];
          float hv = (gg / (1.f + __expf(-gg))) * uu;
          int col = n0 + wc * 32 + j * 16 + lr;
          H[(size_t)(s0 + mrow) * FF + col] = (short)(cvtpk(hv, hv) & 0xffffu);
        }
      }
#undef LOAD1
#undef STORE1
#undef COMPUTE1
}

// ---------------- GEMM2: out[tok] += w * (H * Wd) ----------------
__global__ __launch_bounds__(256) void gemm2_k(
    const short* __restrict__ H, const float* __restrict__ Wd, const float* __restrict__ sWd,
    const int* __restrict__ goff, const int* __restrict__ btok, const float* __restrict__ bw,
    float* __restrict__ out) {
  int g = blockIdx.z;
  int s0g = goff[g], cnt = goff[g + 1] - s0g;
  int mt = blockIdx.y;
  if (mt * BM >= cnt) return;
  int n0 = blockIdx.x * BN;
  const float* wdp = (g < EE) ? Wd + (size_t)g * FF * DD : sWd + (size_t)(g - EE) * FF * DD;

  __shared__ short laA[2][4][BM][8];
  __shared__ short lbB[2][4][BN][8];

  int tid = threadIdx.x;
  int lane = tid & 63;
  int w = tid >> 6;
  int wr = w >> 1, wc = w & 1;
  int lr = lane & 15, lgq = lane >> 4;

  int arow = tid >> 2, aseg = tid & 3;
  int bcol = tid & 63, bkp = tid >> 6;

  int s0 = s0g + mt * BM;
  int aslot = (mt * BM + arow < cnt) ? s0 + arow : s0;
  const short* hrow = H + (size_t)aslot * FF + aseg * 8;
  const float* db = wdp + n0 + bcol;

  f32x4 acc[2][2];
#pragma unroll
  for (int i = 0; i < 2; ++i)
#pragma unroll
    for (int j = 0; j < 2; ++j) acc[i][j] = f32x4{0.f, 0.f, 0.f, 0.f};

  uint4 h0, h1;
  float d0[8], d1[8];

#define LOAD2(S, kt) do { \
    h##S = *reinterpret_cast<const uint4*>(hrow + (kt) * 32); \
    int _kb = (kt) * 32 + bkp * 8; \
    _Pragma("unroll") \
    for (int _i = 0; _i < 8; ++_i) d##S[_i] = db[(size_t)((_kb + _i) * DD)]; \
  } while (0)

#define STORE2(S, b) do { \
    *reinterpret_cast<uint4*>(&laA[b][aseg][arow][0]) = h##S; \
    uint4 _vd; \
    _vd.x = cvtpk(d##S[0], d##S[1]); _vd.y = cvtpk(d##S[2], d##S[3]); \
    _vd.z = cvtpk(d##S[4], d##S[5]); _vd.w = cvtpk(d##S[6], d##S[7]); \
    *reinterpret_cast<uint4*>(&lbB[b][bkp][bcol][0]) = _vd; \
  } while (0)

#define COMPUTE2(b) do { \
    bf16x8 _af[2], _bd[2]; \
    _Pragma("unroll") \
    for (int _i = 0; _i < 2; ++_i) \
      _af[_i] = *reinterpret_cast<const bf16x8*>(&laA[b][lgq][wr * 32 + _i * 16 + lr][0]); \
    _Pragma("unroll") \
    for (int _j = 0; _j < 2; ++_j) \
      _bd[_j] = *reinterpret_cast<const bf16x8*>(&lbB[b][lgq][wc * 32 + _j * 16 + lr][0]); \
    _Pragma("unroll") \
    for (int _i = 0; _i < 2; ++_i) \
      _Pragma("unroll") \
      for (int _j = 0; _j < 2; ++_j) \
        acc[_i][_j] = __builtin_amdgcn_mfma_f32_16x16x32_bf16(_af[_i], _bd[_j], acc[_i][_j], 0, 0, 0); \
  } while (0)

  LOAD2(0, 0);
  LOAD2(1, 1);
  STORE2(0, 0);
  __syncthreads();
#pragma unroll 1
  for (int kt = 0; kt < NT2; kt += 2) {
    if (kt + 2 < NT2) LOAD2(0, kt + 2);
    COMPUTE2(0);
    STORE2(1, 1);
    __syncthreads();
    if (kt + 3 < NT2) LOAD2(1, kt + 3);
    COMPUTE2(1);
    if (kt + 2 < NT2) {
      STORE2(0, 0);
    }
    __syncthreads();
  }

#pragma unroll
  for (int i = 0; i < 2; ++i)
#pragma unroll
    for (int r = 0; r < 4; ++r) {
      int mrow = wr * 32 + i * 16 + lgq * 4 + r;
      if (mt * BM + mrow < cnt) {
        int slot = s0 + mrow;
        int tok = btok[slot];
        float wv = bw[slot];
#pragma unroll
        for (int j = 0; j < 2; ++j) {
          int col = n0 + wc * 32 + j * 16 + lr;
          atomicAdd(&out[(size_t)tok * DD + col], acc[i][j][r] * wv);
        }
      }
    }
#undef LOAD2
#undef STORE2
#undef COMPUTE2
}

extern "C" void kernel_launch(void* const* d_in, const int* in_sizes, int n_in,
                              void* d_out, int out_size, void* d_ws, size_t ws_size,
                              hipStream_t stream) {
  const float* x   = (const float*)d_in[0];
  const float* Wr  = (const float*)d_in[1];
  const float* sWg = (const float*)d_in[2];
  const float* sWu = (const float*)d_in[3];
  const float* sWd = (const float*)d_in[4];
  const float* Wg  = (const float*)d_in[5];
  const float* Wu  = (const float*)d_in[6];
  const float* Wd  = (const float*)d_in[7];
  float* out = (float*)d_out;

  char* wsb = (char*)d_ws;
  size_t off = 0;
  short* H = (short*)(wsb + off);    off += (size_t)NSLOT * FF * 2;     // 16 MB
  int*   top_i = (int*)(wsb + off);  off += (size_t)RSLOT * 4;
  float* top_w = (float*)(wsb + off); off += (size_t)RSLOT * 4;
  int*   btok = (int*)(wsb + off);   off += (size_t)NSLOT * 4;
  float* bwt  = (float*)(wsb + off); off += (size_t)NSLOT * 4;
  int*   cnt  = (int*)(wsb + off);   off += 256;
  int*   fill = (int*)(wsb + off);   off += 256;
  int*   goff = (int*)(wsb + off);   off += 256;

  hipMemsetAsync(cnt, 0, 256, stream);
  router_k<<<N_TOK / 16, 256, 0, stream>>>(x, Wr, top_i, top_w, cnt);
  offsets_k<<<1, 64, 0, stream>>>(cnt, goff, fill);
  scatter_k<<<NSLOT / 256, 256, 0, stream>>>(top_i, top_w, goff, fill, btok, bwt);
  int n4 = out_size / 4;
  initout_k<<<(n4 + 255) / 256, 256, 0, stream>>>(x, out, n4);
  dim3 grid1(FF / BN, N_TOK / BM, NG);
  gemm1_k<<<grid1, 256, 0, stream>>>(x, Wg, Wu, sWg, sWu, goff, btok, H);
  dim3 grid2(DD / BN, N_TOK / BM, NG);
  gemm2_k<<<grid2, 256, 0, stream>>>(H, Wd, sWd, goff, btok, bwt, out);
}